// Round 17
// baseline (93.502 us; speedup 1.0000x reference)
//
#include <hip/hip_runtime.h>
#include <hip/hip_bf16.h>

#define B_N     1024
#define IN_DIM  165
#define EMB_D   150
#define FEAT    315
#define H0_W    325
#define H0_S    384     // padded row stride of h0 (u32), 12*32 = 6*64
#define MB_OUT  10
#define MB_INT  50
#define MROW    64
#define NPROJ   12

typedef __attribute__((ext_vector_type(8))) short short8;
typedef __attribute__((ext_vector_type(4))) float f32x4;

__device__ __forceinline__ ushort f2bf(float f) {
    uint u = __float_as_uint(f);
    return (ushort)((u + 0x7fffu + ((u >> 16) & 1u)) >> 16);
}
__device__ __forceinline__ uint pack_split(float v) {
    ushort h = f2bf(v);
    float hf = __uint_as_float((uint)h << 16);
    ushort l = f2bf(v - hf);
    return (uint)h | ((uint)l << 16);
}
__device__ __forceinline__ float unpack_split(uint u) {
    return __uint_as_float(u << 16) + __uint_as_float(u & 0xffff0000u);
}
__device__ __forceinline__ float bf2f(ushort u) {
    return __uint_as_float((uint)u << 16);
}

// ---------------- standalone build_x (fallback path only) ----------------------
__global__ __launch_bounds__(320) void build_x_kernel(
    const float* __restrict__ ts, const int* __restrict__ cond,
    const float* __restrict__ emb, uint* __restrict__ h0p)
{
    int b = blockIdx.x, t = threadIdx.x;
    if (t < 69) h0p[b * H0_S + FEAT + t] = 0u;   // zero cols [315,384)
    float v;
    if (t < IN_DIM)      v = ts[b * IN_DIM + t];
    else if (t < FEAT)   v = emb[cond[b] * EMB_D + (t - IN_DIM)];
    else return;
    h0p[b * H0_S + t] = pack_split(v);
}

// ---------------- fused prep: pack T (bf16 u16), W1-4 (bf16 u16), build_x ------
// seg0: Tpu u16 [320][512]                    (163840 items)
// seg1: Wb  u32 pairs (1409024 items): W1[384][1536] W2[1536][1024]
//       W3[1024][512] W4[512][256]  (K-pad rows zeroed)
// seg2: h0p build (1024*384 = 393216 items)
__global__ __launch_bounds__(256) void prep_kernel(
    const float* __restrict__ ts, const int* __restrict__ cond,
    const float* __restrict__ emb, const float* __restrict__ T,
    const float* __restrict__ W1, const float* __restrict__ W2,
    const float* __restrict__ W3, const float* __restrict__ W4,
    uint* __restrict__ h0p, ushort* __restrict__ Tpu, uint* __restrict__ Wb)
{
    int i = blockIdx.x * 256 + threadIdx.x;
    if (i < 163840) {
        int k = i >> 9, n = i & 511;
        float v = (k < FEAT && n < 500) ? T[k * 500 + n] : 0.f;
        Tpu[i] = f2bf(v);
    } else if (i < 1572864) {
        int j = i - 163840;
        float v0 = 0.f, v1 = 0.f;
        if (j < 294912) {                       // W1: 384 x 768 pairs
            int k = j / 768, n = (j - k * 768) * 2;
            if (k < H0_W) { v0 = W1[k * 1536 + n]; v1 = W1[k * 1536 + n + 1]; }
        } else if (j < 1081344) {               // W2: 1536 x 512 pairs
            int jj = j - 294912;
            int k = jj >> 9, n = (jj & 511) * 2;
            v0 = W2[k * 1024 + n]; v1 = W2[k * 1024 + n + 1];
        } else if (j < 1343488) {               // W3: 1024 x 256 pairs
            int jj = j - 1081344;
            int k = jj >> 8, n = (jj & 255) * 2;
            v0 = W3[k * 512 + n]; v1 = W3[k * 512 + n + 1];
        } else {                                // W4: 512 x 128 pairs
            int jj = j - 1343488;
            int k = jj >> 7, n = (jj & 127) * 2;
            v0 = W4[k * 256 + n]; v1 = W4[k * 256 + n + 1];
        }
        Wb[j] = (uint)f2bf(v0) | ((uint)f2bf(v1) << 16);
    } else if (i < 1966080) {
        int j = i - 1572864;
        int b = j / H0_S, c = j - b * H0_S;
        uint o = 0u;
        if (c < IN_DIM)    o = pack_split(ts[b * IN_DIM + c]);
        else if (c < FEAT) o = pack_split(emb[cond[b] * EMB_D + (c - IN_DIM)]);
        h0p[b * H0_S + c] = o;
    }
}

// ---------------- 3-term MFMA GEMM (fallback path only) ------------------------
template<int EPI, int PACKED>
__global__ __launch_bounds__(256) void gemm_mfma(
    const uint*  __restrict__ Ap, const void* __restrict__ Bw,
    const float* __restrict__ bias, void* __restrict__ Cout,
    int N, int K, int lda, int ldb, int ldc,
    int kIterTotal, int Ks, float* __restrict__ Pout)
{
    __shared__ ushort Ah[64 * 32], Al[64 * 32], Bh[64 * 32], Bl[64 * 32];

    const int t    = threadIdx.x;
    const int bm   = blockIdx.y << 6;
    const int bn   = blockIdx.x << 6;
    const int wid  = t >> 6, lane = t & 63;
    const int wm   = (wid >> 1) << 5, wn = (wid & 1) << 5;
    const int lm   = lane & 15, lc = lane >> 4;

    const int ar  = t >> 2, ac = t & 3;
    const int bn2 = t & 63, bk = t >> 6;

    const int z   = blockIdx.z;
    const int it0 = z * Ks;
    const int nIt = min(Ks, kIterTotal - it0);

    const int aw = ar  * 32 + ((ac ^ (ar  & 3)) << 3);
    const int bw = bn2 * 32 + ((bk ^ (bn2 & 3)) << 3);
    const int sw = (lc ^ (lm & 3)) << 3;
    const int a0 = (wm + lm)      * 32 + sw;
    const int a1 = (wm + 16 + lm) * 32 + sw;
    const int b0 = (wn + lm)      * 32 + sw;
    const int b1 = (wn + 16 + lm) * 32 + sw;

    uint curA[8], nxtA[8], curB[8], nxtB[8];

    auto loadA = [&](int k0, uint* dst) {
        const uint* p = Ap + (bm + ar) * lda + k0 + (ac << 3);
        uint4 v0 = *(const uint4*)p;
        uint4 v1 = *(const uint4*)(p + 4);
        dst[0] = v0.x; dst[1] = v0.y; dst[2] = v0.z; dst[3] = v0.w;
        dst[4] = v1.x; dst[5] = v1.y; dst[6] = v1.z; dst[7] = v1.w;
    };
    auto loadB = [&](int k0, uint* dst) {
        int kb = k0 + (bk << 3);
        if (PACKED) {
            const uint* p = (const uint*)Bw + kb * ldb + bn + bn2;
            #pragma unroll
            for (int j = 0; j < 8; ++j) dst[j] = p[j * ldb];
        } else {
            const float* p = (const float*)Bw + kb * ldb + bn + bn2;
            bool cok = (bn + bn2) < N;
            #pragma unroll
            for (int j = 0; j < 8; ++j)
                dst[j] = __float_as_uint((cok && (kb + j) < K) ? p[j * ldb] : 0.f);
        }
    };

    f32x4 acc[2][2] = {};

    loadA(it0 << 5, curA);
    loadB(it0 << 5, curB);

    for (int it = 0; it < nIt; ++it) {
        short8 vah, val, vbh, vbl;
        #pragma unroll
        for (int j = 0; j < 8; ++j) {
            uint ua = curA[j];
            vah[j] = (short)(ua & 0xffffu);
            val[j] = (short)(ua >> 16);
            if (PACKED) {
                uint ub = curB[j];
                vbh[j] = (short)(ub & 0xffffu);
                vbl[j] = (short)(ub >> 16);
            } else {
                float v = __uint_as_float(curB[j]);
                ushort h = f2bf(v);
                float hf = __uint_as_float((uint)h << 16);
                vbh[j] = (short)h;
                vbl[j] = (short)f2bf(v - hf);
            }
        }
        __syncthreads();
        *(short8*)&Ah[aw] = vah;
        *(short8*)&Al[aw] = val;
        *(short8*)&Bh[bw] = vbh;
        *(short8*)&Bl[bw] = vbl;
        __syncthreads();

        if (it + 1 < nIt) {
            loadA((it0 + it + 1) << 5, nxtA);
            loadB((it0 + it + 1) << 5, nxtB);
        }

        short8 fah0 = *(const short8*)&Ah[a0];
        short8 fah1 = *(const short8*)&Ah[a1];
        short8 fal0 = *(const short8*)&Al[a0];
        short8 fal1 = *(const short8*)&Al[a1];
        short8 fbh0 = *(const short8*)&Bh[b0];
        short8 fbh1 = *(const short8*)&Bh[b1];
        short8 fbl0 = *(const short8*)&Bl[b0];
        short8 fbl1 = *(const short8*)&Bl[b1];

        acc[0][0] = __builtin_amdgcn_mfma_f32_16x16x32_bf16(fah0, fbh0, acc[0][0], 0, 0, 0);
        acc[0][1] = __builtin_amdgcn_mfma_f32_16x16x32_bf16(fah0, fbh1, acc[0][1], 0, 0, 0);
        acc[1][0] = __builtin_amdgcn_mfma_f32_16x16x32_bf16(fah1, fbh0, acc[1][0], 0, 0, 0);
        acc[1][1] = __builtin_amdgcn_mfma_f32_16x16x32_bf16(fah1, fbh1, acc[1][1], 0, 0, 0);
        acc[0][0] = __builtin_amdgcn_mfma_f32_16x16x32_bf16(fah0, fbl0, acc[0][0], 0, 0, 0);
        acc[0][1] = __builtin_amdgcn_mfma_f32_16x16x32_bf16(fah0, fbl1, acc[0][1], 0, 0, 0);
        acc[1][0] = __builtin_amdgcn_mfma_f32_16x16x32_bf16(fah1, fbl0, acc[1][0], 0, 0, 0);
        acc[1][1] = __builtin_amdgcn_mfma_f32_16x16x32_bf16(fah1, fbl1, acc[1][1], 0, 0, 0);
        acc[0][0] = __builtin_amdgcn_mfma_f32_16x16x32_bf16(fal0, fbh0, acc[0][0], 0, 0, 0);
        acc[0][1] = __builtin_amdgcn_mfma_f32_16x16x32_bf16(fal0, fbh1, acc[0][1], 0, 0, 0);
        acc[1][0] = __builtin_amdgcn_mfma_f32_16x16x32_bf16(fal1, fbh0, acc[1][0], 0, 0, 0);
        acc[1][1] = __builtin_amdgcn_mfma_f32_16x16x32_bf16(fal1, fbh1, acc[1][1], 0, 0, 0);

        #pragma unroll
        for (int j = 0; j < 8; ++j) { curA[j] = nxtA[j]; curB[j] = nxtB[j]; }
    }

    #pragma unroll
    for (int mi = 0; mi < 2; ++mi)
    #pragma unroll
    for (int ni = 0; ni < 2; ++ni)
    #pragma unroll
    for (int r = 0; r < 4; ++r) {
        int row = bm + wm + mi * 16 + lc * 4 + r;
        int col = bn + wn + ni * 16 + lm;
        float v = acc[mi][ni][r];
        if (EPI == 0) {
            v += bias[col];
            v = (v > 0.f) ? v : 0.2f * v;
            ((uint*)Cout)[row * ldc + col] = pack_split(v);
        } else {
            if (col < N) {
                int o = col / MB_INT, kk = col - o * MB_INT;
                ((float*)Cout)[(o * B_N + row) * MROW + kk] = v;
            }
        }
    }
}

// ---------------- 2-term MFMA GEMM, BK=64 (T + W1): A split u32, B bf16 --------
// 16 MFMA + 12 ds_read_b128 + 2 barriers per 64-K slab. 24KB LDS.
// EPI 0: bf16 out with bias+lrelu. EPI 1: fp32 M2-permuted store (col<500).
// gridDim.z>1: fp32 partials P[z][1024][N] (N=512 for T: unguarded).
template<int EPI>
__global__ __launch_bounds__(256) void gemm_mfma2k64(
    const uint* __restrict__ Ap, const ushort* __restrict__ Bw,
    const float* __restrict__ bias, void* __restrict__ Cout,
    int N, int lda, int ldb, int ldc,
    int kIterTotal, int Ks, float* __restrict__ Pout)
{
    __shared__ ushort Ah[64 * 64], Al[64 * 64], Bh[64 * 64];

    const int t    = threadIdx.x;
    const int bm   = blockIdx.y << 6;
    const int bn   = blockIdx.x << 6;
    const int wid  = t >> 6, lane = t & 63;
    const int wm   = (wid >> 1) << 5, wn = (wid & 1) << 5;
    const int lm   = lane & 15, lc = lane >> 4;

    const int ar  = t >> 2, ac = t & 3;     // A: row, chunks {ac, ac+4}
    const int bn2 = t & 63, bk = t >> 6;    // B: n-col, k-chunks {bk, bk+4}

    const int z   = blockIdx.z;
    const int it0 = z * Ks;
    const int nIt = min(Ks, kIterTotal - it0);

    const int aw0 = ar  * 64 + (((ac)     ^ (ar  & 7)) << 3);
    const int aw1 = ar  * 64 + (((ac + 4) ^ (ar  & 7)) << 3);
    const int bw0 = bn2 * 64 + (((bk)     ^ (bn2 & 7)) << 3);
    const int bw1 = bn2 * 64 + (((bk + 4) ^ (bn2 & 7)) << 3);
    const int ra0 = wm + lm, ra1 = wm + 16 + lm;
    const int rb0 = wn + lm, rb1 = wn + 16 + lm;
    const int a00 = ra0 * 64 + (((lc)     ^ (ra0 & 7)) << 3);
    const int a10 = ra1 * 64 + (((lc)     ^ (ra1 & 7)) << 3);
    const int a01 = ra0 * 64 + (((lc + 4) ^ (ra0 & 7)) << 3);
    const int a11 = ra1 * 64 + (((lc + 4) ^ (ra1 & 7)) << 3);
    const int b00 = rb0 * 64 + (((lc)     ^ (rb0 & 7)) << 3);
    const int b10 = rb1 * 64 + (((lc)     ^ (rb1 & 7)) << 3);
    const int b01 = rb0 * 64 + (((lc + 4) ^ (rb0 & 7)) << 3);
    const int b11 = rb1 * 64 + (((lc + 4) ^ (rb1 & 7)) << 3);

    uint   curA[16], nxtA[16];
    ushort curB[16], nxtB[16];

    auto loadA = [&](int k0, uint* dst) {
        const uint* p = Ap + (size_t)(bm + ar) * lda + k0 + (ac << 3);
        uint4 v0 = *(const uint4*)p;
        uint4 v1 = *(const uint4*)(p + 4);
        uint4 v2 = *(const uint4*)(p + 32);
        uint4 v3 = *(const uint4*)(p + 36);
        dst[0] = v0.x; dst[1] = v0.y; dst[2]  = v0.z; dst[3]  = v0.w;
        dst[4] = v1.x; dst[5] = v1.y; dst[6]  = v1.z; dst[7]  = v1.w;
        dst[8] = v2.x; dst[9] = v2.y; dst[10] = v2.z; dst[11] = v2.w;
        dst[12] = v3.x; dst[13] = v3.y; dst[14] = v3.z; dst[15] = v3.w;
    };
    auto loadB = [&](int k0, ushort* dst) {
        const ushort* p = Bw + (size_t)(k0 + (bk << 3)) * ldb + bn + bn2;
        #pragma unroll
        for (int j = 0; j < 8; ++j) dst[j] = p[j * ldb];
        const ushort* p2 = p + 32 * ldb;
        #pragma unroll
        for (int j = 0; j < 8; ++j) dst[8 + j] = p2[j * ldb];
    };

    f32x4 acc[2][2] = {};

    loadA(it0 << 6, curA);
    loadB(it0 << 6, curB);

    for (int it = 0; it < nIt; ++it) {
        short8 vah0, val0, vah1, val1, vb0, vb1;
        #pragma unroll
        for (int j = 0; j < 8; ++j) {
            uint ua = curA[j];
            vah0[j] = (short)(ua & 0xffffu);
            val0[j] = (short)(ua >> 16);
            uint ub = curA[8 + j];
            vah1[j] = (short)(ub & 0xffffu);
            val1[j] = (short)(ub >> 16);
            vb0[j] = (short)curB[j];
            vb1[j] = (short)curB[8 + j];
        }
        __syncthreads();
        *(short8*)&Ah[aw0] = vah0;
        *(short8*)&Ah[aw1] = vah1;
        *(short8*)&Al[aw0] = val0;
        *(short8*)&Al[aw1] = val1;
        *(short8*)&Bh[bw0] = vb0;
        *(short8*)&Bh[bw1] = vb1;
        __syncthreads();

        if (it + 1 < nIt) {
            loadA((it0 + it + 1) << 6, nxtA);
            loadB((it0 + it + 1) << 6, nxtB);
        }

        // k-subtile 0
        {
            short8 fah0 = *(const short8*)&Ah[a00];
            short8 fah1 = *(const short8*)&Ah[a10];
            short8 fal0 = *(const short8*)&Al[a00];
            short8 fal1 = *(const short8*)&Al[a10];
            short8 fb0  = *(const short8*)&Bh[b00];
            short8 fb1  = *(const short8*)&Bh[b10];
            acc[0][0] = __builtin_amdgcn_mfma_f32_16x16x32_bf16(fah0, fb0, acc[0][0], 0, 0, 0);
            acc[0][1] = __builtin_amdgcn_mfma_f32_16x16x32_bf16(fah0, fb1, acc[0][1], 0, 0, 0);
            acc[1][0] = __builtin_amdgcn_mfma_f32_16x16x32_bf16(fah1, fb0, acc[1][0], 0, 0, 0);
            acc[1][1] = __builtin_amdgcn_mfma_f32_16x16x32_bf16(fah1, fb1, acc[1][1], 0, 0, 0);
            acc[0][0] = __builtin_amdgcn_mfma_f32_16x16x32_bf16(fal0, fb0, acc[0][0], 0, 0, 0);
            acc[0][1] = __builtin_amdgcn_mfma_f32_16x16x32_bf16(fal0, fb1, acc[0][1], 0, 0, 0);
            acc[1][0] = __builtin_amdgcn_mfma_f32_16x16x32_bf16(fal1, fb0, acc[1][0], 0, 0, 0);
            acc[1][1] = __builtin_amdgcn_mfma_f32_16x16x32_bf16(fal1, fb1, acc[1][1], 0, 0, 0);
        }
        // k-subtile 1
        {
            short8 fah0 = *(const short8*)&Ah[a01];
            short8 fah1 = *(const short8*)&Ah[a11];
            short8 fal0 = *(const short8*)&Al[a01];
            short8 fal1 = *(const short8*)&Al[a11];
            short8 fb0  = *(const short8*)&Bh[b01];
            short8 fb1  = *(const short8*)&Bh[b11];
            acc[0][0] = __builtin_amdgcn_mfma_f32_16x16x32_bf16(fah0, fb0, acc[0][0], 0, 0, 0);
            acc[0][1] = __builtin_amdgcn_mfma_f32_16x16x32_bf16(fah0, fb1, acc[0][1], 0, 0, 0);
            acc[1][0] = __builtin_amdgcn_mfma_f32_16x16x32_bf16(fah1, fb0, acc[1][0], 0, 0, 0);
            acc[1][1] = __builtin_amdgcn_mfma_f32_16x16x32_bf16(fah1, fb1, acc[1][1], 0, 0, 0);
            acc[0][0] = __builtin_amdgcn_mfma_f32_16x16x32_bf16(fal0, fb0, acc[0][0], 0, 0, 0);
            acc[0][1] = __builtin_amdgcn_mfma_f32_16x16x32_bf16(fal0, fb1, acc[0][1], 0, 0, 0);
            acc[1][0] = __builtin_amdgcn_mfma_f32_16x16x32_bf16(fal1, fb0, acc[1][0], 0, 0, 0);
            acc[1][1] = __builtin_amdgcn_mfma_f32_16x16x32_bf16(fal1, fb1, acc[1][1], 0, 0, 0);
        }

        #pragma unroll
        for (int j = 0; j < 16; ++j) { curA[j] = nxtA[j]; curB[j] = nxtB[j]; }
    }

    if (gridDim.z > 1) {
        float* P = Pout + (size_t)z * B_N * N;
        #pragma unroll
        for (int mi = 0; mi < 2; ++mi)
        #pragma unroll
        for (int ni = 0; ni < 2; ++ni)
        #pragma unroll
        for (int r = 0; r < 4; ++r) {
            int row = bm + wm + mi * 16 + lc * 4 + r;
            int col = bn + wn + ni * 16 + lm;
            P[row * N + col] = acc[mi][ni][r];
        }
        return;
    }

    #pragma unroll
    for (int mi = 0; mi < 2; ++mi)
    #pragma unroll
    for (int ni = 0; ni < 2; ++ni)
    #pragma unroll
    for (int r = 0; r < 4; ++r) {
        int row = bm + wm + mi * 16 + lc * 4 + r;
        int col = bn + wn + ni * 16 + lm;
        float v = acc[mi][ni][r];
        if (EPI == 0) {
            v += bias[col];
            v = (v > 0.f) ? v : 0.2f * v;
            ((ushort*)Cout)[row * ldc + col] = f2bf(v);
        } else {
            if (col < 500) {
                int o = col / MB_INT, kk = col - o * MB_INT;
                ((float*)Cout)[(o * B_N + row) * MROW + kk] = v;
            }
        }
    }
}

// ---------------- 1-term MFMA GEMM (W2-4): A bf16, B bf16, BK=64 ---------------
__global__ __launch_bounds__(256) void gemm_mfma1(
    const ushort* __restrict__ Ab, const ushort* __restrict__ Bw,
    const float* __restrict__ bias, ushort* __restrict__ Cout,
    int N, int lda, int ldb, int ldc,
    int kIterTotal, int Ks, float* __restrict__ Pout)
{
    __shared__ ushort Ah[64 * 64], Bh[64 * 64];

    const int t    = threadIdx.x;
    const int bm   = blockIdx.y << 6;
    const int bn   = blockIdx.x << 6;
    const int wid  = t >> 6, lane = t & 63;
    const int wm   = (wid >> 1) << 5, wn = (wid & 1) << 5;
    const int lm   = lane & 15, lc = lane >> 4;

    const int ar  = t >> 2, ac = t & 3;
    const int bn2 = t & 63, bk = t >> 6;

    const int z   = blockIdx.z;
    const int it0 = z * Ks;
    const int nIt = min(Ks, kIterTotal - it0);

    const int aw0 = ar  * 64 + (((ac)     ^ (ar  & 7)) << 3);
    const int aw1 = ar  * 64 + (((ac + 4) ^ (ar  & 7)) << 3);
    const int bw0 = bn2 * 64 + (((bk)     ^ (bn2 & 7)) << 3);
    const int bw1 = bn2 * 64 + (((bk + 4) ^ (bn2 & 7)) << 3);
    const int ra0 = wm + lm, ra1 = wm + 16 + lm;
    const int rb0 = wn + lm, rb1 = wn + 16 + lm;
    const int a00 = ra0 * 64 + (((lc)     ^ (ra0 & 7)) << 3);
    const int a10 = ra1 * 64 + (((lc)     ^ (ra1 & 7)) << 3);
    const int a01 = ra0 * 64 + (((lc + 4) ^ (ra0 & 7)) << 3);
    const int a11 = ra1 * 64 + (((lc + 4) ^ (ra1 & 7)) << 3);
    const int b00 = rb0 * 64 + (((lc)     ^ (rb0 & 7)) << 3);
    const int b10 = rb1 * 64 + (((lc)     ^ (rb1 & 7)) << 3);
    const int b01 = rb0 * 64 + (((lc + 4) ^ (rb0 & 7)) << 3);
    const int b11 = rb1 * 64 + (((lc + 4) ^ (rb1 & 7)) << 3);

    short8 curA[2], nxtA[2];
    ushort curB[16], nxtB[16];

    auto loadA = [&](int k0, short8* dst) {
        const ushort* p = Ab + (size_t)(bm + ar) * lda + k0 + (ac << 3);
        dst[0] = *(const short8*)p;
        dst[1] = *(const short8*)(p + 32);
    };
    auto loadB = [&](int k0, ushort* dst) {
        const ushort* p = Bw + (size_t)(k0 + (bk << 3)) * ldb + bn + bn2;
        #pragma unroll
        for (int j = 0; j < 8; ++j) dst[j] = p[j * ldb];
        const ushort* p2 = p + 32 * ldb;
        #pragma unroll
        for (int j = 0; j < 8; ++j) dst[8 + j] = p2[j * ldb];
    };

    f32x4 acc[2][2] = {};

    loadA(it0 << 6, curA);
    loadB(it0 << 6, curB);

    for (int it = 0; it < nIt; ++it) {
        short8 vb0, vb1;
        #pragma unroll
        for (int j = 0; j < 8; ++j) {
            vb0[j] = (short)curB[j];
            vb1[j] = (short)curB[8 + j];
        }
        __syncthreads();
        *(short8*)&Ah[aw0] = curA[0];
        *(short8*)&Ah[aw1] = curA[1];
        *(short8*)&Bh[bw0] = vb0;
        *(short8*)&Bh[bw1] = vb1;
        __syncthreads();

        if (it + 1 < nIt) {
            loadA((it0 + it + 1) << 6, nxtA);
            loadB((it0 + it + 1) << 6, nxtB);
        }

        {
            short8 fa0 = *(const short8*)&Ah[a00];
            short8 fa1 = *(const short8*)&Ah[a10];
            short8 fb0 = *(const short8*)&Bh[b00];
            short8 fb1 = *(const short8*)&Bh[b10];
            acc[0][0] = __builtin_amdgcn_mfma_f32_16x16x32_bf16(fa0, fb0, acc[0][0], 0, 0, 0);
            acc[0][1] = __builtin_amdgcn_mfma_f32_16x16x32_bf16(fa0, fb1, acc[0][1], 0, 0, 0);
            acc[1][0] = __builtin_amdgcn_mfma_f32_16x16x32_bf16(fa1, fb0, acc[1][0], 0, 0, 0);
            acc[1][1] = __builtin_amdgcn_mfma_f32_16x16x32_bf16(fa1, fb1, acc[1][1], 0, 0, 0);
        }
        {
            short8 fa0 = *(const short8*)&Ah[a01];
            short8 fa1 = *(const short8*)&Ah[a11];
            short8 fb0 = *(const short8*)&Bh[b01];
            short8 fb1 = *(const short8*)&Bh[b11];
            acc[0][0] = __builtin_amdgcn_mfma_f32_16x16x32_bf16(fa0, fb0, acc[0][0], 0, 0, 0);
            acc[0][1] = __builtin_amdgcn_mfma_f32_16x16x32_bf16(fa0, fb1, acc[0][1], 0, 0, 0);
            acc[1][0] = __builtin_amdgcn_mfma_f32_16x16x32_bf16(fa1, fb0, acc[1][0], 0, 0, 0);
            acc[1][1] = __builtin_amdgcn_mfma_f32_16x16x32_bf16(fa1, fb1, acc[1][1], 0, 0, 0);
        }

        curA[0] = nxtA[0]; curA[1] = nxtA[1];
        #pragma unroll
        for (int j = 0; j < 16; ++j) curB[j] = nxtB[j];
    }

    if (gridDim.z > 1) {
        float* P = Pout + (size_t)z * B_N * N;
        #pragma unroll
        for (int mi = 0; mi < 2; ++mi)
        #pragma unroll
        for (int ni = 0; ni < 2; ++ni)
        #pragma unroll
        for (int r = 0; r < 4; ++r) {
            int row = bm + wm + mi * 16 + lc * 4 + r;
            int col = bn + wn + ni * 16 + lm;
            P[row * N + col] = acc[mi][ni][r];
        }
        return;
    }

    #pragma unroll
    for (int mi = 0; mi < 2; ++mi)
    #pragma unroll
    for (int ni = 0; ni < 2; ++ni)
    #pragma unroll
    for (int r = 0; r < 4; ++r) {
        int row = bm + wm + mi * 16 + lc * 4 + r;
        int col = bn + wn + ni * 16 + lm;
        float v = acc[mi][ni][r] + bias[col];
        v = (v > 0.f) ? v : 0.2f * v;
        Cout[row * ldc + col] = f2bf(v);
    }
}

// ---------------- split-K epilogue (bf16 out) ----------------------------------
template<int FINAL>
__global__ __launch_bounds__(256) void epi_pack_kernel(
    const float* __restrict__ P, const float* __restrict__ bias,
    ushort* __restrict__ outp, int n4, int S,
    const float* __restrict__ W5, const float* __restrict__ b5,
    float* __restrict__ out)
{
    const int c4 = blockIdx.x * 64 + (threadIdx.x & 63);
    const int r  = blockIdx.y * 4 + (threadIdx.x >> 6);
    const int idx = r * n4 + c4;
    const float4* P4 = (const float4*)P;
    float4 v = P4[idx];
    for (int s = 1; s < S; ++s) {
        float4 w = P4[(size_t)s * B_N * n4 + idx];
        v.x += w.x; v.y += w.y; v.z += w.z; v.w += w.w;
    }
    float4 bb = ((const float4*)bias)[c4];
    v.x += bb.x; v.y += bb.y; v.z += bb.z; v.w += bb.w;
    v.x = (v.x > 0.f) ? v.x : 0.2f * v.x;
    v.y = (v.y > 0.f) ? v.y : 0.2f * v.y;
    v.z = (v.z > 0.f) ? v.z : 0.2f * v.z;
    v.w = (v.w > 0.f) ? v.w : 0.2f * v.w;
    if (FINAL) {
        const float4 w5 = ((const float4*)W5)[c4];
        float s = v.x * w5.x + v.y * w5.y + v.z * w5.z + v.w * w5.w;
        #pragma unroll
        for (int off = 32; off > 0; off >>= 1)
            s += __shfl_xor(s, off);
        if ((threadIdx.x & 63) == 0) {
            float z = s + b5[0];
            out[r] = 1.f / (1.f + __expf(-z));
        }
    } else {
        ushort4 o;
        o.x = f2bf(v.x); o.y = f2bf(v.y); o.z = f2bf(v.z); o.w = f2bf(v.w);
        ((ushort4*)outp)[idx] = o;
    }
}

// ---------------- sign projections + fused T split-K reduce --------------------
__device__ __constant__ const unsigned long long PMASK[NPROJ] = {
    0x2B5F1E3A4B6C7DULL, 0x19D4A7C3E85B26ULL, 0x3E6A1D59F0B483ULL,
    0x07C2F8A135E9D6ULL, 0x2A94E6B7D01C3FULL, 0x35B8D2041A7E6CULL,
    0x1CE07B3F68A5D2ULL, 0x22F1A4C85D93E0ULL, 0x0B67D3E92C50F8ULL,
    0x38A0C5171E4B9DULL, 0x114E92F6A3D078ULL, 0x2D73B0E84F169AULL
};

template<int J0>
__device__ __forceinline__ void proj3(const float* __restrict__ row, float* s) {
    float s0 = 0.f, s1 = 0.f, s2 = 0.f;
    #pragma unroll
    for (int k = 0; k < MB_INT; ++k) {
        float v = row[k];
        if ((PMASK[J0]     >> k) & 1ULL) s0 -= v; else s0 += v;
        if ((PMASK[J0 + 4] >> k) & 1ULL) s1 -= v; else s1 += v;
        if ((PMASK[J0 + 8] >> k) & 1ULL) s2 -= v; else s2 += v;
    }
    s[0] = s0; s[1] = s1; s[2] = s2;
}

// ST>1: read T-GEMM partials from P ([s][1024][512]), sum, write M2, project.
// ST==1: read M2 directly (T wrote it).
__global__ __launch_bounds__(256) void proj_kernel(
    float* __restrict__ M2, float* __restrict__ Rproj,
    const float* __restrict__ P, int ST)
{
    __shared__ float Ls[64 * 53];
    const int rt = blockIdx.x, o = blockIdx.y, t = threadIdx.x;

    #pragma unroll
    for (int i = 0; i < 13; ++i) {
        int idx = t + i * 256;
        int r = idx / 52, k = idx - r * 52;
        int row = rt * 64 + r;
        float v = 0.f;
        if (k < MB_INT) {
            if (ST > 1) {
                const float* q = P + (size_t)row * 512 + o * MB_INT + k;
                v = q[0];
                for (int s = 1; s < ST; ++s) v += q[(size_t)s * B_N * 512];
                M2[(o * B_N + row) * MROW + k] = v;
            } else {
                v = M2[(o * B_N + row) * MROW + k];
            }
        }
        Ls[r * 53 + k] = v;
    }
    __syncthreads();

    const int r = t & 63, j0 = t >> 6;
    float s[3];
    if      (j0 == 0) proj3<0>(&Ls[r * 53], s);
    else if (j0 == 1) proj3<1>(&Ls[r * 53], s);
    else if (j0 == 2) proj3<2>(&Ls[r * 53], s);
    else              proj3<3>(&Ls[r * 53], s);

    float* dst = Rproj + (size_t)(o * B_N + rt * 64 + r) * NPROJ;
    dst[j0] = s[0]; dst[j0 + 4] = s[1]; dst[j0 + 8] = s[2];
}

// ---------------- pairwise L1 + exp, projection-pruned -------------------------
__global__ __launch_bounds__(256) void pairwise_kernel(
    const float* __restrict__ M2, const float* __restrict__ Rproj,
    float* __restrict__ part)
{
    __shared__ float Lp[32 * NPROJ];
    const int grp = blockIdx.x, o = blockIdx.y, ch = blockIdx.z;
    const int t = threadIdx.x, wid = t >> 6, lane = t & 63;

    if (t < 96)
        ((float4*)Lp)[t] = ((const float4*)(Rproj + (size_t)(o * B_N + ch * 32) * NPROJ))[t];
    __syncthreads();

    const int b = (grp * 4 + wid) * 64 + lane;

    const float4* Ar = (const float4*)(M2 + (size_t)(o * B_N + b) * MROW);
    float4 A0 = Ar[0], A1 = Ar[1], A2 = Ar[2],  A3 = Ar[3];
    float4 A4 = Ar[4], A5 = Ar[5], A6 = Ar[6],  A7 = Ar[7];
    float4 A8 = Ar[8], A9 = Ar[9], A10 = Ar[10], A11 = Ar[11];
    float2 A12 = *(const float2*)((const float*)Ar + 48);

    const float4* Pr = (const float4*)(Rproj + (size_t)(o * B_N + b) * NPROJ);
    float4 P0 = Pr[0], P1 = Pr[1], P2 = Pr[2];

    const int selfstep = (ch == (b >> 5)) ? (b & 31) : -1;
    float acc = (selfstep >= 0) ? 1.f : 0.f;

    const float* Bbase = M2 + (size_t)(o * B_N + ch * 32) * MROW;

    for (int b2 = 0; b2 < 32; ++b2) {
        const float4* qp = (const float4*)&Lp[b2 * NPROJ];
        float4 q0 = qp[0], q1 = qp[1], q2 = qp[2];
        float d0 = fabsf(P0.x - q0.x), d1 = fabsf(P0.y - q0.y);
        float d2 = fabsf(P0.z - q0.z), d3 = fabsf(P0.w - q0.w);
        float d4 = fabsf(P1.x - q1.x), d5 = fabsf(P1.y - q1.y);
        float d6 = fabsf(P1.z - q1.z), d7 = fabsf(P1.w - q1.w);
        float d8 = fabsf(P2.x - q2.x), d9 = fabsf(P2.y - q2.y);
        float dA = fabsf(P2.z - q2.z), dB = fabsf(P2.w - q2.w);
        float m0 = fmaxf(fmaxf(d0, d1), fmaxf(d2, d3));
        float m1 = fmaxf(fmaxf(d4, d5), fmaxf(d6, d7));
        float m2 = fmaxf(fmaxf(d8, d9), fmaxf(dA, dB));
        float dmax = fmaxf(fmaxf(m0, m1), m2);

        if (__all(dmax > 110.f || b2 == selfstep)) continue;

        const float4* q = (const float4*)(Bbase + b2 * MROW);
        float4 s = {0.f, 0.f, 0.f, 0.f};
        float4 v;
        v = q[0];  s.x += fabsf(A0.x - v.x);  s.y += fabsf(A0.y - v.y);  s.z += fabsf(A0.z - v.z);  s.w += fabsf(A0.w - v.w);
        v = q[1];  s.x += fabsf(A1.x - v.x);  s.y += fabsf(A1.y - v.y);  s.z += fabsf(A1.z - v.z);  s.w += fabsf(A1.w - v.w);
        v = q[2];  s.x += fabsf(A2.x - v.x);  s.y += fabsf(A2.y - v.y);  s.z += fabsf(A2.z - v.z);  s.w += fabsf(A2.w - v.w);
        v = q[3];  s.x += fabsf(A3.x - v.x);  s.y += fabsf(A3.y - v.y);  s.z += fabsf(A3.z - v.z);  s.w += fabsf(A3.w - v.w);
        v = q[4];  s.x += fabsf(A4.x - v.x);  s.y += fabsf(A4.y - v.y);  s.z += fabsf(A4.z - v.z);  s.w += fabsf(A4.w - v.w);
        v = q[5];  s.x += fabsf(A5.x - v.x);  s.y += fabsf(A5.y - v.y);  s.z += fabsf(A5.z - v.z);  s.w += fabsf(A5.w - v.w);
        v = q[6];  s.x += fabsf(A6.x - v.x);  s.y += fabsf(A6.y - v.y);  s.z += fabsf(A6.z - v.z);  s.w += fabsf(A6.w - v.w);
        v = q[7];  s.x += fabsf(A7.x - v.x);  s.y += fabsf(A7.y - v.y);  s.z += fabsf(A7.z - v.z);  s.w += fabsf(A7.w - v.w);
        v = q[8];  s.x += fabsf(A8.x - v.x);  s.y += fabsf(A8.y - v.y);  s.z += fabsf(A8.z - v.z);  s.w += fabsf(A8.w - v.w);
        v = q[9];  s.x += fabsf(A9.x - v.x);  s.y += fabsf(A9.y - v.y);  s.z += fabsf(A9.z - v.z);  s.w += fabsf(A9.w - v.w);
        v = q[10]; s.x += fabsf(A10.x - v.x); s.y += fabsf(A10.y - v.y); s.z += fabsf(A10.z - v.z); s.w += fabsf(A10.w - v.w);
        v = q[11]; s.x += fabsf(A11.x - v.x); s.y += fabsf(A11.y - v.y); s.z += fabsf(A11.z - v.z); s.w += fabsf(A11.w - v.w);
        v = q[12]; s.x += fabsf(A12.x - v.x); s.y += fabsf(A12.y - v.y);
        float d = (s.x + s.y) + (s.z + s.w);
        float e = __expf(-d);
        acc += (b2 == selfstep) ? 0.f : e;
    }
    part[(ch * MB_OUT + o) * B_N + b] = acc;
}

// ---------------- reduce 32 partials into h0p[:, 315:325] ----------------------
__global__ __launch_bounds__(256) void mb_reduce_kernel(
    const float* __restrict__ part, uint* __restrict__ h0p)
{
    int i = blockIdx.x * 256 + threadIdx.x;
    if (i < MB_OUT * B_N) {
        int o = i / B_N, b = i - o * B_N;
        float s = 0.f;
        #pragma unroll
        for (int ch = 0; ch < 32; ++ch)
            s += part[(ch * MB_OUT + o) * B_N + b];
        h0p[b * H0_S + FEAT + o] = pack_split(s);
    }
}

// ---------------- final layer fallback -----------------------------------------
template<int U16>
__global__ __launch_bounds__(256) void final_kernel(
    const void* __restrict__ h4v, const float* __restrict__ W5,
    const float* __restrict__ b5, float* __restrict__ out)
{
    const int wave = threadIdx.x >> 6;
    const int lane = threadIdx.x & 63;
    const int row  = blockIdx.x * 4 + wave;

    const float4 w = ((const float4*)W5)[lane];
    float s;
    if (U16) {
        const ushort* h4 = (const ushort*)h4v;
        ushort4 h = ((const ushort4*)(h4 + (size_t)row * 256))[lane];
        s = bf2f(h.x) * w.x + bf2f(h.y) * w.y + bf2f(h.z) * w.z + bf2f(h.w) * w.w;
    } else {
        const uint* h4 = (const uint*)h4v;
        uint4 h = ((const uint4*)(h4 + (size_t)row * 256))[lane];
        s = unpack_split(h.x) * w.x + unpack_split(h.y) * w.y
          + unpack_split(h.z) * w.z + unpack_split(h.w) * w.w;
    }
    #pragma unroll
    for (int off = 32; off > 0; off >>= 1)
        s += __shfl_xor(s, off);
    if (lane == 0) {
        float z = s + b5[0];
        out[row] = 1.f / (1.f + __expf(-z));
    }
}

// ---------------- launch -------------------------------------------------------
extern "C" void kernel_launch(void* const* d_in, const int* in_sizes, int n_in,
                              void* d_out, int out_size, void* d_ws, size_t ws_size,
                              hipStream_t stream)
{
    const float* ts   = (const float*)d_in[0];
    const int*   cond = (const int*)  d_in[1];
    const float* emb  = (const float*)d_in[2];
    const float* T    = (const float*)d_in[3];
    const float* W1   = (const float*)d_in[4];
    const float* b1   = (const float*)d_in[5];
    const float* W2   = (const float*)d_in[6];
    const float* b2   = (const float*)d_in[7];
    const float* W3   = (const float*)d_in[8];
    const float* b3   = (const float*)d_in[9];
    const float* W4   = (const float*)d_in[10];
    const float* b4   = (const float*)d_in[11];
    const float* W5   = (const float*)d_in[12];
    const float* b5   = (const float*)d_in[13];
    float* out = (float*)d_out;

    // workspace (4-byte units)
    uint*  h0p  = (uint*)d_ws;             // 1024*384 = 393216
    float* M2   = (float*)(h0p + 393216);  // 655360
    uint*  h1p  = (uint*)(M2 + 655360);    // 1572864
    uint*  h2p  = h1p + 1572864;           // 1048576
    uint*  h3p  = (uint*)M2;               // alias
    uint*  h4p  = h1p;                     // alias
    float* part  = (float*)h1p;            // alias: 327680 (dead before W1)
    float* Rproj = part + 327680;          // alias: 122880 (dead before W1)
    const size_t baseU = 393216 + 655360 + 1572864 + 1048576;   // 3670016

    // packed weights: Tpu (bf16 u16, 163840 = 81920 u32) + Wb (bf16 pairs)
    ushort* Tpu = (ushort*)((uint*)d_ws + baseU);   // 320*512 ushort
    uint* Wb = (uint*)d_ws + baseU + 81920;         // 1409024 u32
    ushort* W1b = (ushort*)Wb;             // 384*1536
    ushort* W2b = W1b + 589824;            // 1536*1024
    ushort* W3b = W2b + 1572864;           // 1024*512
    ushort* W4b = W3b + 524288;            // 512*256
    const size_t packU = 81920 + 1409024;  // 1490944
    const bool packed = (ws_size / 4) >= (baseU + packU);

    const size_t pbase = packed ? baseU + packU : baseU;
    size_t capU = (ws_size / 4 > pbase) ? ws_size / 4 - pbase : 0;
    float* Pbuf = (float*)((uint*)d_ws + pbase);

    auto fits = [&](int s, int N) { return (size_t)s * B_N * N <= capU; };
    const int ST = fits(2, 512)  ? 2 : 1;
    const int S1 = fits(3, 1536) ? 3 : (fits(2, 1536) ? 2 : 1);
    const int S2 = fits(3, 1024) ? 3 : (fits(2, 1024) ? 2 : 1);
    const int S3 = fits(4, 512)  ? 4 : (fits(2, 512)  ? 2 : 1);
    const int S4 = fits(4, 256)  ? 4 : (fits(2, 256)  ? 2 : 1);

    if (packed) {
        prep_kernel<<<7680, 256, 0, stream>>>(ts, cond, emb, T, W1, W2, W3, W4,
                                              h0p, Tpu, Wb);

        // T: 2-term BK=64 (split A x bf16 T), split-K; partials reduced in proj
        {
            int kit = 5, ks = (kit + ST - 1) / ST;
            dim3 g(8, 16, ST);
            gemm_mfma2k64<1><<<g, 256, 0, stream>>>(h0p, Tpu, nullptr, M2,
                                                    512, H0_S, 512, 0, kit, ks, Pbuf);
        }
        { dim3 g(16, MB_OUT); proj_kernel<<<g, 256, 0, stream>>>(M2, Rproj, Pbuf, ST); }
        { dim3 g(4, MB_OUT, 32); pairwise_kernel<<<g, 256, 0, stream>>>(M2, Rproj, part); }
        mb_reduce_kernel<<<(MB_OUT * B_N + 255) / 256, 256, 0, stream>>>(part, h0p);

        ushort* h1u = (ushort*)h1p;
        ushort* h2u = (ushort*)h2p;
        ushort* h3u = (ushort*)h3p;
        ushort* h4u = (ushort*)h4p;

        // W1: 2-term BK=64 (A = split u32 h0p, K padded to 384), bf16 out
        {
            int kit = 6, ks = (kit + S1 - 1) / S1;
            dim3 g(24, 16, S1);
            gemm_mfma2k64<0><<<g, 256, 0, stream>>>(h0p, W1b, b1, h1u, 1536, H0_S,
                                                    1536, 1536, kit, ks, Pbuf);
            if (S1 > 1) {
                dim3 ge(6, 256);
                epi_pack_kernel<0><<<ge, 256, 0, stream>>>(Pbuf, b1, h1u, 384, S1,
                                                           nullptr, nullptr, nullptr);
            }
        }
        // W2/W3/W4: 1-term bf16, BK=64; lda = producing layer's N; kit in 64-K units
        auto runL1 = [&](const ushort* in, const ushort* Wbp, const float* bia,
                         ushort* outp, int N, int lda, int kit, int S, bool fin) {
            int ks = (kit + S - 1) / S;
            dim3 g(N / 64, 16, S);
            gemm_mfma1<<<g, 256, 0, stream>>>(in, Wbp, bia, outp, N, lda, N, N,
                                              kit, ks, Pbuf);
            if (S > 1) {
                dim3 ge((N / 4) / 64, B_N / 4);
                if (fin)
                    epi_pack_kernel<1><<<ge, 256, 0, stream>>>(Pbuf, bia, outp, N / 4, S,
                                                               W5, b5, out);
                else
                    epi_pack_kernel<0><<<ge, 256, 0, stream>>>(Pbuf, bia, outp, N / 4, S,
                                                               nullptr, nullptr, nullptr);
            }
        };
        runL1(h1u, W2b, b2, h2u, 1024, 1536, 24, S2, false);
        runL1(h2u, W3b, b3, h3u,  512, 1024, 16, S3, false);
        runL1(h3u, W4b, b4, h4u,  256,  512,  8, S4, true);
        if (S4 <= 1)
            final_kernel<1><<<B_N / 4, 256, 0, stream>>>(h4u, W5, b5, out);
    } else {
        // fallback: unpacked guarded 3-term everywhere, unsplit, u32 activations
        build_x_kernel<<<B_N, 320, 0, stream>>>(ts, cond, emb, h0p);
        { dim3 g(8, 16); gemm_mfma<1,0><<<g, 256, 0, stream>>>(
              h0p, T, nullptr, M2, 500, FEAT, H0_S, 500, 0, 10, 10, Pbuf); }
        { dim3 g(16, MB_OUT); proj_kernel<<<g, 256, 0, stream>>>(M2, Rproj, nullptr, 1); }
        { dim3 g(4, MB_OUT, 32); pairwise_kernel<<<g, 256, 0, stream>>>(M2, Rproj, part); }
        mb_reduce_kernel<<<(MB_OUT * B_N + 255) / 256, 256, 0, stream>>>(part, h0p);
        { dim3 g(24, 16); gemm_mfma<0,0><<<g, 256, 0, stream>>>(
              h0p, W1, b1, h1p, 1536, H0_W, H0_S, 1536, 1536, 11, 11, Pbuf); }
        { dim3 g(16, 16); gemm_mfma<0,0><<<g, 256, 0, stream>>>(
              h1p, W2, b2, h2p, 1024, 1536, 1536, 1024, 1024, 48, 48, Pbuf); }
        { dim3 g(8, 16);  gemm_mfma<0,0><<<g, 256, 0, stream>>>(
              h2p, W3, b3, h3p, 512, 1024, 1024, 512, 512, 32, 32, Pbuf); }
        { dim3 g(4, 16);  gemm_mfma<0,0><<<g, 256, 0, stream>>>(
              h3p, W4, b4, h4p, 256, 512, 512, 256, 256, 16, 16, Pbuf); }
        final_kernel<0><<<B_N / 4, 256, 0, stream>>>(h4p, W5, b5, out);
    }
}

// Round 18
// 92.339 us; speedup vs baseline: 1.0126x; 1.0126x over previous
//
#include <hip/hip_runtime.h>
#include <hip/hip_bf16.h>

#define B_N     1024
#define IN_DIM  165
#define EMB_D   150
#define FEAT    315
#define H0_W    325
#define H0_S    352     // padded row stride of h0 (u32), 11*32
#define MB_OUT  10
#define MB_INT  50
#define MROW    64
#define NPROJ   12

typedef __attribute__((ext_vector_type(8))) short short8;
typedef __attribute__((ext_vector_type(4))) float f32x4;

__device__ __forceinline__ ushort f2bf(float f) {
    uint u = __float_as_uint(f);
    return (ushort)((u + 0x7fffu + ((u >> 16) & 1u)) >> 16);
}
__device__ __forceinline__ uint pack_split(float v) {
    ushort h = f2bf(v);
    float hf = __uint_as_float((uint)h << 16);
    ushort l = f2bf(v - hf);
    return (uint)h | ((uint)l << 16);
}
__device__ __forceinline__ float unpack_split(uint u) {
    return __uint_as_float(u << 16) + __uint_as_float(u & 0xffff0000u);
}
__device__ __forceinline__ float bf2f(ushort u) {
    return __uint_as_float((uint)u << 16);
}

// ---------------- standalone build_x (fallback path only) ----------------------
__global__ __launch_bounds__(320) void build_x_kernel(
    const float* __restrict__ ts, const int* __restrict__ cond,
    const float* __restrict__ emb, uint* __restrict__ h0p)
{
    int b = blockIdx.x, t = threadIdx.x;
    if (t < 37) h0p[b * H0_S + FEAT + t] = 0u;
    float v;
    if (t < IN_DIM)      v = ts[b * IN_DIM + t];
    else if (t < FEAT)   v = emb[cond[b] * EMB_D + (t - IN_DIM)];
    else return;
    h0p[b * H0_S + t] = pack_split(v);
}

// ---------------- fused prep: pack T (bf16 u16), W1-4 (bf16 u16), build_x ------
__global__ __launch_bounds__(256) void prep_kernel(
    const float* __restrict__ ts, const int* __restrict__ cond,
    const float* __restrict__ emb, const float* __restrict__ T,
    const float* __restrict__ W1, const float* __restrict__ W2,
    const float* __restrict__ W3, const float* __restrict__ W4,
    uint* __restrict__ h0p, ushort* __restrict__ Tpu, uint* __restrict__ Wb)
{
    int i = blockIdx.x * 256 + threadIdx.x;
    if (i < 163840) {
        int k = i >> 9, n = i & 511;
        float v = (k < FEAT && n < 500) ? T[k * 500 + n] : 0.f;
        Tpu[i] = f2bf(v);
    } else if (i < 1548288) {
        int j = i - 163840;
        float v0 = 0.f, v1 = 0.f;
        if (j < 270336) {                       // W1: 352 x 768 pairs
            int k = j / 768, n = (j - k * 768) * 2;
            if (k < H0_W) { v0 = W1[k * 1536 + n]; v1 = W1[k * 1536 + n + 1]; }
        } else if (j < 1056768) {               // W2: 1536 x 512 pairs
            int jj = j - 270336;
            int k = jj >> 9, n = (jj & 511) * 2;
            v0 = W2[k * 1024 + n]; v1 = W2[k * 1024 + n + 1];
        } else if (j < 1318912) {               // W3: 1024 x 256 pairs
            int jj = j - 1056768;
            int k = jj >> 8, n = (jj & 255) * 2;
            v0 = W3[k * 512 + n]; v1 = W3[k * 512 + n + 1];
        } else {                                // W4: 512 x 128 pairs
            int jj = j - 1318912;
            int k = jj >> 7, n = (jj & 127) * 2;
            v0 = W4[k * 256 + n]; v1 = W4[k * 256 + n + 1];
        }
        Wb[j] = (uint)f2bf(v0) | ((uint)f2bf(v1) << 16);
    } else if (i < 1908736) {
        int j = i - 1548288;
        int b = j / H0_S, c = j - b * H0_S;
        uint o = 0u;
        if (c < IN_DIM)    o = pack_split(ts[b * IN_DIM + c]);
        else if (c < FEAT) o = pack_split(emb[cond[b] * EMB_D + (c - IN_DIM)]);
        h0p[b * H0_S + c] = o;
    }
}

// ---------------- 3-term MFMA GEMM (fallback path only) ------------------------
template<int EPI, int PACKED>
__global__ __launch_bounds__(256) void gemm_mfma(
    const uint*  __restrict__ Ap, const void* __restrict__ Bw,
    const float* __restrict__ bias, void* __restrict__ Cout,
    int N, int K, int lda, int ldb, int ldc,
    int kIterTotal, int Ks, float* __restrict__ Pout)
{
    __shared__ ushort Ah[64 * 32], Al[64 * 32], Bh[64 * 32], Bl[64 * 32];

    const int t    = threadIdx.x;
    const int bm   = blockIdx.y << 6;
    const int bn   = blockIdx.x << 6;
    const int wid  = t >> 6, lane = t & 63;
    const int wm   = (wid >> 1) << 5, wn = (wid & 1) << 5;
    const int lm   = lane & 15, lc = lane >> 4;

    const int ar  = t >> 2, ac = t & 3;
    const int bn2 = t & 63, bk = t >> 6;

    const int z   = blockIdx.z;
    const int it0 = z * Ks;
    const int nIt = min(Ks, kIterTotal - it0);

    const int aw = ar  * 32 + ((ac ^ (ar  & 3)) << 3);
    const int bw = bn2 * 32 + ((bk ^ (bn2 & 3)) << 3);
    const int sw = (lc ^ (lm & 3)) << 3;
    const int a0 = (wm + lm)      * 32 + sw;
    const int a1 = (wm + 16 + lm) * 32 + sw;
    const int b0 = (wn + lm)      * 32 + sw;
    const int b1 = (wn + 16 + lm) * 32 + sw;

    uint curA[8], nxtA[8], curB[8], nxtB[8];

    auto loadA = [&](int k0, uint* dst) {
        const uint* p = Ap + (bm + ar) * lda + k0 + (ac << 3);
        uint4 v0 = *(const uint4*)p;
        uint4 v1 = *(const uint4*)(p + 4);
        dst[0] = v0.x; dst[1] = v0.y; dst[2] = v0.z; dst[3] = v0.w;
        dst[4] = v1.x; dst[5] = v1.y; dst[6] = v1.z; dst[7] = v1.w;
    };
    auto loadB = [&](int k0, uint* dst) {
        int kb = k0 + (bk << 3);
        if (PACKED) {
            const uint* p = (const uint*)Bw + kb * ldb + bn + bn2;
            #pragma unroll
            for (int j = 0; j < 8; ++j) dst[j] = p[j * ldb];
        } else {
            const float* p = (const float*)Bw + kb * ldb + bn + bn2;
            bool cok = (bn + bn2) < N;
            #pragma unroll
            for (int j = 0; j < 8; ++j)
                dst[j] = __float_as_uint((cok && (kb + j) < K) ? p[j * ldb] : 0.f);
        }
    };

    f32x4 acc[2][2] = {};

    loadA(it0 << 5, curA);
    loadB(it0 << 5, curB);

    for (int it = 0; it < nIt; ++it) {
        short8 vah, val, vbh, vbl;
        #pragma unroll
        for (int j = 0; j < 8; ++j) {
            uint ua = curA[j];
            vah[j] = (short)(ua & 0xffffu);
            val[j] = (short)(ua >> 16);
            if (PACKED) {
                uint ub = curB[j];
                vbh[j] = (short)(ub & 0xffffu);
                vbl[j] = (short)(ub >> 16);
            } else {
                float v = __uint_as_float(curB[j]);
                ushort h = f2bf(v);
                float hf = __uint_as_float((uint)h << 16);
                vbh[j] = (short)h;
                vbl[j] = (short)f2bf(v - hf);
            }
        }
        __syncthreads();
        *(short8*)&Ah[aw] = vah;
        *(short8*)&Al[aw] = val;
        *(short8*)&Bh[bw] = vbh;
        *(short8*)&Bl[bw] = vbl;
        __syncthreads();

        if (it + 1 < nIt) {
            loadA((it0 + it + 1) << 5, nxtA);
            loadB((it0 + it + 1) << 5, nxtB);
        }

        short8 fah0 = *(const short8*)&Ah[a0];
        short8 fah1 = *(const short8*)&Ah[a1];
        short8 fal0 = *(const short8*)&Al[a0];
        short8 fal1 = *(const short8*)&Al[a1];
        short8 fbh0 = *(const short8*)&Bh[b0];
        short8 fbh1 = *(const short8*)&Bh[b1];
        short8 fbl0 = *(const short8*)&Bl[b0];
        short8 fbl1 = *(const short8*)&Bl[b1];

        acc[0][0] = __builtin_amdgcn_mfma_f32_16x16x32_bf16(fah0, fbh0, acc[0][0], 0, 0, 0);
        acc[0][1] = __builtin_amdgcn_mfma_f32_16x16x32_bf16(fah0, fbh1, acc[0][1], 0, 0, 0);
        acc[1][0] = __builtin_amdgcn_mfma_f32_16x16x32_bf16(fah1, fbh0, acc[1][0], 0, 0, 0);
        acc[1][1] = __builtin_amdgcn_mfma_f32_16x16x32_bf16(fah1, fbh1, acc[1][1], 0, 0, 0);
        acc[0][0] = __builtin_amdgcn_mfma_f32_16x16x32_bf16(fah0, fbl0, acc[0][0], 0, 0, 0);
        acc[0][1] = __builtin_amdgcn_mfma_f32_16x16x32_bf16(fah0, fbl1, acc[0][1], 0, 0, 0);
        acc[1][0] = __builtin_amdgcn_mfma_f32_16x16x32_bf16(fah1, fbl0, acc[1][0], 0, 0, 0);
        acc[1][1] = __builtin_amdgcn_mfma_f32_16x16x32_bf16(fah1, fbl1, acc[1][1], 0, 0, 0);
        acc[0][0] = __builtin_amdgcn_mfma_f32_16x16x32_bf16(fal0, fbh0, acc[0][0], 0, 0, 0);
        acc[0][1] = __builtin_amdgcn_mfma_f32_16x16x32_bf16(fal0, fbh1, acc[0][1], 0, 0, 0);
        acc[1][0] = __builtin_amdgcn_mfma_f32_16x16x32_bf16(fal1, fbh0, acc[1][0], 0, 0, 0);
        acc[1][1] = __builtin_amdgcn_mfma_f32_16x16x32_bf16(fal1, fbh1, acc[1][1], 0, 0, 0);

        #pragma unroll
        for (int j = 0; j < 8; ++j) { curA[j] = nxtA[j]; curB[j] = nxtB[j]; }
    }

    #pragma unroll
    for (int mi = 0; mi < 2; ++mi)
    #pragma unroll
    for (int ni = 0; ni < 2; ++ni)
    #pragma unroll
    for (int r = 0; r < 4; ++r) {
        int row = bm + wm + mi * 16 + lc * 4 + r;
        int col = bn + wn + ni * 16 + lm;
        float v = acc[mi][ni][r];
        if (EPI == 0) {
            v += bias[col];
            v = (v > 0.f) ? v : 0.2f * v;
            ((uint*)Cout)[row * ldc + col] = pack_split(v);
        } else {
            if (col < N) {
                int o = col / MB_INT, kk = col - o * MB_INT;
                ((float*)Cout)[(o * B_N + row) * MROW + kk] = v;
            }
        }
    }
}

// ---------------- 2-term MFMA GEMM (T + W1): A split u32, B bf16 ---------------
// EPI 0: bf16 out with bias+lrelu. EPI 1: fp32 M2-permuted store (col<500).
// gridDim.z>1: fp32 partials P[z][1024][N] (N=512 for T: unguarded).
template<int EPI>
__global__ __launch_bounds__(256) void gemm_mfma2(
    const uint* __restrict__ Ap, const ushort* __restrict__ Bw,
    const float* __restrict__ bias, void* __restrict__ Cout,
    int N, int lda, int ldb, int ldc,
    int kIterTotal, int Ks, float* __restrict__ Pout)
{
    __shared__ ushort Ah[64 * 32], Al[64 * 32], Bh[64 * 32];

    const int t    = threadIdx.x;
    const int bm   = blockIdx.y << 6;
    const int bn   = blockIdx.x << 6;
    const int wid  = t >> 6, lane = t & 63;
    const int wm   = (wid >> 1) << 5, wn = (wid & 1) << 5;
    const int lm   = lane & 15, lc = lane >> 4;

    const int ar  = t >> 2, ac = t & 3;
    const int bn2 = t & 63, bk = t >> 6;

    const int z   = blockIdx.z;
    const int it0 = z * Ks;
    const int nIt = min(Ks, kIterTotal - it0);

    const int aw = ar  * 32 + ((ac ^ (ar  & 3)) << 3);
    const int bw = bn2 * 32 + ((bk ^ (bn2 & 3)) << 3);
    const int sw = (lc ^ (lm & 3)) << 3;
    const int a0 = (wm + lm)      * 32 + sw;
    const int a1 = (wm + 16 + lm) * 32 + sw;
    const int b0 = (wn + lm)      * 32 + sw;
    const int b1 = (wn + 16 + lm) * 32 + sw;

    uint   curA[8], nxtA[8];
    ushort curB[8], nxtB[8];

    auto loadA = [&](int k0, uint* dst) {
        const uint* p = Ap + (bm + ar) * lda + k0 + (ac << 3);
        uint4 v0 = *(const uint4*)p;
        uint4 v1 = *(const uint4*)(p + 4);
        dst[0] = v0.x; dst[1] = v0.y; dst[2] = v0.z; dst[3] = v0.w;
        dst[4] = v1.x; dst[5] = v1.y; dst[6] = v1.z; dst[7] = v1.w;
    };
    auto loadB = [&](int k0, ushort* dst) {
        const ushort* p = Bw + (k0 + (bk << 3)) * ldb + bn + bn2;
        #pragma unroll
        for (int j = 0; j < 8; ++j) dst[j] = p[j * ldb];
    };

    f32x4 acc[2][2] = {};

    loadA(it0 << 5, curA);
    loadB(it0 << 5, curB);

    for (int it = 0; it < nIt; ++it) {
        short8 vah, val, vbh;
        #pragma unroll
        for (int j = 0; j < 8; ++j) {
            uint ua = curA[j];
            vah[j] = (short)(ua & 0xffffu);
            val[j] = (short)(ua >> 16);
            vbh[j] = (short)curB[j];
        }
        __syncthreads();
        *(short8*)&Ah[aw] = vah;
        *(short8*)&Al[aw] = val;
        *(short8*)&Bh[bw] = vbh;
        __syncthreads();

        if (it + 1 < nIt) {
            loadA((it0 + it + 1) << 5, nxtA);
            loadB((it0 + it + 1) << 5, nxtB);
        }

        short8 fah0 = *(const short8*)&Ah[a0];
        short8 fah1 = *(const short8*)&Ah[a1];
        short8 fal0 = *(const short8*)&Al[a0];
        short8 fal1 = *(const short8*)&Al[a1];
        short8 fbh0 = *(const short8*)&Bh[b0];
        short8 fbh1 = *(const short8*)&Bh[b1];

        acc[0][0] = __builtin_amdgcn_mfma_f32_16x16x32_bf16(fah0, fbh0, acc[0][0], 0, 0, 0);
        acc[0][1] = __builtin_amdgcn_mfma_f32_16x16x32_bf16(fah0, fbh1, acc[0][1], 0, 0, 0);
        acc[1][0] = __builtin_amdgcn_mfma_f32_16x16x32_bf16(fah1, fbh0, acc[1][0], 0, 0, 0);
        acc[1][1] = __builtin_amdgcn_mfma_f32_16x16x32_bf16(fah1, fbh1, acc[1][1], 0, 0, 0);
        acc[0][0] = __builtin_amdgcn_mfma_f32_16x16x32_bf16(fal0, fbh0, acc[0][0], 0, 0, 0);
        acc[0][1] = __builtin_amdgcn_mfma_f32_16x16x32_bf16(fal0, fbh1, acc[0][1], 0, 0, 0);
        acc[1][0] = __builtin_amdgcn_mfma_f32_16x16x32_bf16(fal1, fbh0, acc[1][0], 0, 0, 0);
        acc[1][1] = __builtin_amdgcn_mfma_f32_16x16x32_bf16(fal1, fbh1, acc[1][1], 0, 0, 0);

        #pragma unroll
        for (int j = 0; j < 8; ++j) { curA[j] = nxtA[j]; curB[j] = nxtB[j]; }
    }

    if (gridDim.z > 1) {
        float* P = Pout + (size_t)z * B_N * N;
        #pragma unroll
        for (int mi = 0; mi < 2; ++mi)
        #pragma unroll
        for (int ni = 0; ni < 2; ++ni)
        #pragma unroll
        for (int r = 0; r < 4; ++r) {
            int row = bm + wm + mi * 16 + lc * 4 + r;
            int col = bn + wn + ni * 16 + lm;
            P[row * N + col] = acc[mi][ni][r];
        }
        return;
    }

    #pragma unroll
    for (int mi = 0; mi < 2; ++mi)
    #pragma unroll
    for (int ni = 0; ni < 2; ++ni)
    #pragma unroll
    for (int r = 0; r < 4; ++r) {
        int row = bm + wm + mi * 16 + lc * 4 + r;
        int col = bn + wn + ni * 16 + lm;
        float v = acc[mi][ni][r];
        if (EPI == 0) {
            v += bias[col];
            v = (v > 0.f) ? v : 0.2f * v;
            ((ushort*)Cout)[row * ldc + col] = f2bf(v);
        } else {
            if (col < 500) {
                int o = col / MB_INT, kk = col - o * MB_INT;
                ((float*)Cout)[(o * B_N + row) * MROW + kk] = v;
            }
        }
    }
}

// ---------------- 1-term MFMA GEMM (W2-4): A bf16, B bf16, BK=64 ---------------
// 8 MFMA + 8 ds_read_b128 per k-iter, 2 barriers per 64-K slab. 16KB LDS.
__global__ __launch_bounds__(256) void gemm_mfma1(
    const ushort* __restrict__ Ab, const ushort* __restrict__ Bw,
    const float* __restrict__ bias, ushort* __restrict__ Cout,
    int N, int lda, int ldb, int ldc,
    int kIterTotal, int Ks, float* __restrict__ Pout)
{
    __shared__ ushort Ah[64 * 64], Bh[64 * 64];

    const int t    = threadIdx.x;
    const int bm   = blockIdx.y << 6;
    const int bn   = blockIdx.x << 6;
    const int wid  = t >> 6, lane = t & 63;
    const int wm   = (wid >> 1) << 5, wn = (wid & 1) << 5;
    const int lm   = lane & 15, lc = lane >> 4;

    const int ar  = t >> 2, ac = t & 3;     // A: row, chunks {ac, ac+4}
    const int bn2 = t & 63, bk = t >> 6;    // B: n-col, k-chunks {bk, bk+4}

    const int z   = blockIdx.z;
    const int it0 = z * Ks;
    const int nIt = min(Ks, kIterTotal - it0);

    const int aw0 = ar  * 64 + (((ac)     ^ (ar  & 7)) << 3);
    const int aw1 = ar  * 64 + (((ac + 4) ^ (ar  & 7)) << 3);
    const int bw0 = bn2 * 64 + (((bk)     ^ (bn2 & 7)) << 3);
    const int bw1 = bn2 * 64 + (((bk + 4) ^ (bn2 & 7)) << 3);
    const int ra0 = wm + lm, ra1 = wm + 16 + lm;
    const int rb0 = wn + lm, rb1 = wn + 16 + lm;
    const int a00 = ra0 * 64 + (((lc)     ^ (ra0 & 7)) << 3);
    const int a10 = ra1 * 64 + (((lc)     ^ (ra1 & 7)) << 3);
    const int a01 = ra0 * 64 + (((lc + 4) ^ (ra0 & 7)) << 3);
    const int a11 = ra1 * 64 + (((lc + 4) ^ (ra1 & 7)) << 3);
    const int b00 = rb0 * 64 + (((lc)     ^ (rb0 & 7)) << 3);
    const int b10 = rb1 * 64 + (((lc)     ^ (rb1 & 7)) << 3);
    const int b01 = rb0 * 64 + (((lc + 4) ^ (rb0 & 7)) << 3);
    const int b11 = rb1 * 64 + (((lc + 4) ^ (rb1 & 7)) << 3);

    short8 curA[2], nxtA[2];
    ushort curB[16], nxtB[16];

    auto loadA = [&](int k0, short8* dst) {
        const ushort* p = Ab + (size_t)(bm + ar) * lda + k0 + (ac << 3);
        dst[0] = *(const short8*)p;
        dst[1] = *(const short8*)(p + 32);
    };
    auto loadB = [&](int k0, ushort* dst) {
        const ushort* p = Bw + (size_t)(k0 + (bk << 3)) * ldb + bn + bn2;
        #pragma unroll
        for (int j = 0; j < 8; ++j) dst[j] = p[j * ldb];
        const ushort* p2 = p + 32 * ldb;
        #pragma unroll
        for (int j = 0; j < 8; ++j) dst[8 + j] = p2[j * ldb];
    };

    f32x4 acc[2][2] = {};

    loadA(it0 << 6, curA);
    loadB(it0 << 6, curB);

    for (int it = 0; it < nIt; ++it) {
        short8 vb0, vb1;
        #pragma unroll
        for (int j = 0; j < 8; ++j) {
            vb0[j] = (short)curB[j];
            vb1[j] = (short)curB[8 + j];
        }
        __syncthreads();
        *(short8*)&Ah[aw0] = curA[0];
        *(short8*)&Ah[aw1] = curA[1];
        *(short8*)&Bh[bw0] = vb0;
        *(short8*)&Bh[bw1] = vb1;
        __syncthreads();

        if (it + 1 < nIt) {
            loadA((it0 + it + 1) << 6, &nxtA[0]);
            loadB((it0 + it + 1) << 6, nxtB);
        }

        {
            short8 fa0 = *(const short8*)&Ah[a00];
            short8 fa1 = *(const short8*)&Ah[a10];
            short8 fb0 = *(const short8*)&Bh[b00];
            short8 fb1 = *(const short8*)&Bh[b10];
            acc[0][0] = __builtin_amdgcn_mfma_f32_16x16x32_bf16(fa0, fb0, acc[0][0], 0, 0, 0);
            acc[0][1] = __builtin_amdgcn_mfma_f32_16x16x32_bf16(fa0, fb1, acc[0][1], 0, 0, 0);
            acc[1][0] = __builtin_amdgcn_mfma_f32_16x16x32_bf16(fa1, fb0, acc[1][0], 0, 0, 0);
            acc[1][1] = __builtin_amdgcn_mfma_f32_16x16x32_bf16(fa1, fb1, acc[1][1], 0, 0, 0);
        }
        {
            short8 fa0 = *(const short8*)&Ah[a01];
            short8 fa1 = *(const short8*)&Ah[a11];
            short8 fb0 = *(const short8*)&Bh[b01];
            short8 fb1 = *(const short8*)&Bh[b11];
            acc[0][0] = __builtin_amdgcn_mfma_f32_16x16x32_bf16(fa0, fb0, acc[0][0], 0, 0, 0);
            acc[0][1] = __builtin_amdgcn_mfma_f32_16x16x32_bf16(fa0, fb1, acc[0][1], 0, 0, 0);
            acc[1][0] = __builtin_amdgcn_mfma_f32_16x16x32_bf16(fa1, fb0, acc[1][0], 0, 0, 0);
            acc[1][1] = __builtin_amdgcn_mfma_f32_16x16x32_bf16(fa1, fb1, acc[1][1], 0, 0, 0);
        }

        curA[0] = nxtA[0]; curA[1] = nxtA[1];
        #pragma unroll
        for (int j = 0; j < 16; ++j) curB[j] = nxtB[j];
    }

    if (gridDim.z > 1) {
        float* P = Pout + (size_t)z * B_N * N;
        #pragma unroll
        for (int mi = 0; mi < 2; ++mi)
        #pragma unroll
        for (int ni = 0; ni < 2; ++ni)
        #pragma unroll
        for (int r = 0; r < 4; ++r) {
            int row = bm + wm + mi * 16 + lc * 4 + r;
            int col = bn + wn + ni * 16 + lm;
            P[row * N + col] = acc[mi][ni][r];
        }
        return;
    }

    #pragma unroll
    for (int mi = 0; mi < 2; ++mi)
    #pragma unroll
    for (int ni = 0; ni < 2; ++ni)
    #pragma unroll
    for (int r = 0; r < 4; ++r) {
        int row = bm + wm + mi * 16 + lc * 4 + r;
        int col = bn + wn + ni * 16 + lm;
        float v = acc[mi][ni][r] + bias[col];
        v = (v > 0.f) ? v : 0.2f * v;
        Cout[row * ldc + col] = f2bf(v);
    }
}

// ---------------- split-K epilogue (bf16 out) ----------------------------------
template<int FINAL>
__global__ __launch_bounds__(256) void epi_pack_kernel(
    const float* __restrict__ P, const float* __restrict__ bias,
    ushort* __restrict__ outp, int n4, int S,
    const float* __restrict__ W5, const float* __restrict__ b5,
    float* __restrict__ out)
{
    const int c4 = blockIdx.x * 64 + (threadIdx.x & 63);
    const int r  = blockIdx.y * 4 + (threadIdx.x >> 6);
    const int idx = r * n4 + c4;
    const float4* P4 = (const float4*)P;
    float4 v = P4[idx];
    for (int s = 1; s < S; ++s) {
        float4 w = P4[(size_t)s * B_N * n4 + idx];
        v.x += w.x; v.y += w.y; v.z += w.z; v.w += w.w;
    }
    float4 bb = ((const float4*)bias)[c4];
    v.x += bb.x; v.y += bb.y; v.z += bb.z; v.w += bb.w;
    v.x = (v.x > 0.f) ? v.x : 0.2f * v.x;
    v.y = (v.y > 0.f) ? v.y : 0.2f * v.y;
    v.z = (v.z > 0.f) ? v.z : 0.2f * v.z;
    v.w = (v.w > 0.f) ? v.w : 0.2f * v.w;
    if (FINAL) {
        const float4 w5 = ((const float4*)W5)[c4];
        float s = v.x * w5.x + v.y * w5.y + v.z * w5.z + v.w * w5.w;
        #pragma unroll
        for (int off = 32; off > 0; off >>= 1)
            s += __shfl_xor(s, off);
        if ((threadIdx.x & 63) == 0) {
            float z = s + b5[0];
            out[r] = 1.f / (1.f + __expf(-z));
        }
    } else {
        ushort4 o;
        o.x = f2bf(v.x); o.y = f2bf(v.y); o.z = f2bf(v.z); o.w = f2bf(v.w);
        ((ushort4*)outp)[idx] = o;
    }
}

// ---------------- sign projections + fused T split-K reduce --------------------
__device__ __constant__ const unsigned long long PMASK[NPROJ] = {
    0x2B5F1E3A4B6C7DULL, 0x19D4A7C3E85B26ULL, 0x3E6A1D59F0B483ULL,
    0x07C2F8A135E9D6ULL, 0x2A94E6B7D01C3FULL, 0x35B8D2041A7E6CULL,
    0x1CE07B3F68A5D2ULL, 0x22F1A4C85D93E0ULL, 0x0B67D3E92C50F8ULL,
    0x38A0C5171E4B9DULL, 0x114E92F6A3D078ULL, 0x2D73B0E84F169AULL
};

template<int J0>
__device__ __forceinline__ void proj3(const float* __restrict__ row, float* s) {
    float s0 = 0.f, s1 = 0.f, s2 = 0.f;
    #pragma unroll
    for (int k = 0; k < MB_INT; ++k) {
        float v = row[k];
        if ((PMASK[J0]     >> k) & 1ULL) s0 -= v; else s0 += v;
        if ((PMASK[J0 + 4] >> k) & 1ULL) s1 -= v; else s1 += v;
        if ((PMASK[J0 + 8] >> k) & 1ULL) s2 -= v; else s2 += v;
    }
    s[0] = s0; s[1] = s1; s[2] = s2;
}

// ST>1: read T-GEMM partials from P ([s][1024][512]), sum, write M2, project.
// ST==1: read M2 directly (T wrote it).
__global__ __launch_bounds__(256) void proj_kernel(
    float* __restrict__ M2, float* __restrict__ Rproj,
    const float* __restrict__ P, int ST)
{
    __shared__ float Ls[64 * 53];
    const int rt = blockIdx.x, o = blockIdx.y, t = threadIdx.x;

    #pragma unroll
    for (int i = 0; i < 13; ++i) {
        int idx = t + i * 256;
        int r = idx / 52, k = idx - r * 52;
        int row = rt * 64 + r;
        float v = 0.f;
        if (k < MB_INT) {
            if (ST > 1) {
                const float* q = P + (size_t)row * 512 + o * MB_INT + k;
                v = q[0];
                for (int s = 1; s < ST; ++s) v += q[(size_t)s * B_N * 512];
                M2[(o * B_N + row) * MROW + k] = v;
            } else {
                v = M2[(o * B_N + row) * MROW + k];
            }
        }
        Ls[r * 53 + k] = v;
    }
    __syncthreads();

    const int r = t & 63, j0 = t >> 6;
    float s[3];
    if      (j0 == 0) proj3<0>(&Ls[r * 53], s);
    else if (j0 == 1) proj3<1>(&Ls[r * 53], s);
    else if (j0 == 2) proj3<2>(&Ls[r * 53], s);
    else              proj3<3>(&Ls[r * 53], s);

    float* dst = Rproj + (size_t)(o * B_N + rt * 64 + r) * NPROJ;
    dst[j0] = s[0]; dst[j0 + 4] = s[1]; dst[j0 + 8] = s[2];
}

// ---------------- pairwise L1 + exp, projection-pruned -------------------------
__global__ __launch_bounds__(256) void pairwise_kernel(
    const float* __restrict__ M2, const float* __restrict__ Rproj,
    float* __restrict__ part)
{
    __shared__ float Lp[32 * NPROJ];
    const int grp = blockIdx.x, o = blockIdx.y, ch = blockIdx.z;
    const int t = threadIdx.x, wid = t >> 6, lane = t & 63;

    if (t < 96)
        ((float4*)Lp)[t] = ((const float4*)(Rproj + (size_t)(o * B_N + ch * 32) * NPROJ))[t];
    __syncthreads();

    const int b = (grp * 4 + wid) * 64 + lane;

    const float4* Ar = (const float4*)(M2 + (size_t)(o * B_N + b) * MROW);
    float4 A0 = Ar[0], A1 = Ar[1], A2 = Ar[2],  A3 = Ar[3];
    float4 A4 = Ar[4], A5 = Ar[5], A6 = Ar[6],  A7 = Ar[7];
    float4 A8 = Ar[8], A9 = Ar[9], A10 = Ar[10], A11 = Ar[11];
    float2 A12 = *(const float2*)((const float*)Ar + 48);

    const float4* Pr = (const float4*)(Rproj + (size_t)(o * B_N + b) * NPROJ);
    float4 P0 = Pr[0], P1 = Pr[1], P2 = Pr[2];

    const int selfstep = (ch == (b >> 5)) ? (b & 31) : -1;
    float acc = (selfstep >= 0) ? 1.f : 0.f;

    const float* Bbase = M2 + (size_t)(o * B_N + ch * 32) * MROW;

    for (int b2 = 0; b2 < 32; ++b2) {
        const float4* qp = (const float4*)&Lp[b2 * NPROJ];
        float4 q0 = qp[0], q1 = qp[1], q2 = qp[2];
        float d0 = fabsf(P0.x - q0.x), d1 = fabsf(P0.y - q0.y);
        float d2 = fabsf(P0.z - q0.z), d3 = fabsf(P0.w - q0.w);
        float d4 = fabsf(P1.x - q1.x), d5 = fabsf(P1.y - q1.y);
        float d6 = fabsf(P1.z - q1.z), d7 = fabsf(P1.w - q1.w);
        float d8 = fabsf(P2.x - q2.x), d9 = fabsf(P2.y - q2.y);
        float dA = fabsf(P2.z - q2.z), dB = fabsf(P2.w - q2.w);
        float m0 = fmaxf(fmaxf(d0, d1), fmaxf(d2, d3));
        float m1 = fmaxf(fmaxf(d4, d5), fmaxf(d6, d7));
        float m2 = fmaxf(fmaxf(d8, d9), fmaxf(dA, dB));
        float dmax = fmaxf(fmaxf(m0, m1), m2);

        if (__all(dmax > 110.f || b2 == selfstep)) continue;

        const float4* q = (const float4*)(Bbase + b2 * MROW);
        float4 s = {0.f, 0.f, 0.f, 0.f};
        float4 v;
        v = q[0];  s.x += fabsf(A0.x - v.x);  s.y += fabsf(A0.y - v.y);  s.z += fabsf(A0.z - v.z);  s.w += fabsf(A0.w - v.w);
        v = q[1];  s.x += fabsf(A1.x - v.x);  s.y += fabsf(A1.y - v.y);  s.z += fabsf(A1.z - v.z);  s.w += fabsf(A1.w - v.w);
        v = q[2];  s.x += fabsf(A2.x - v.x);  s.y += fabsf(A2.y - v.y);  s.z += fabsf(A2.z - v.z);  s.w += fabsf(A2.w - v.w);
        v = q[3];  s.x += fabsf(A3.x - v.x);  s.y += fabsf(A3.y - v.y);  s.z += fabsf(A3.z - v.z);  s.w += fabsf(A3.w - v.w);
        v = q[4];  s.x += fabsf(A4.x - v.x);  s.y += fabsf(A4.y - v.y);  s.z += fabsf(A4.z - v.z);  s.w += fabsf(A4.w - v.w);
        v = q[5];  s.x += fabsf(A5.x - v.x);  s.y += fabsf(A5.y - v.y);  s.z += fabsf(A5.z - v.z);  s.w += fabsf(A5.w - v.w);
        v = q[6];  s.x += fabsf(A6.x - v.x);  s.y += fabsf(A6.y - v.y);  s.z += fabsf(A6.z - v.z);  s.w += fabsf(A6.w - v.w);
        v = q[7];  s.x += fabsf(A7.x - v.x);  s.y += fabsf(A7.y - v.y);  s.z += fabsf(A7.z - v.z);  s.w += fabsf(A7.w - v.w);
        v = q[8];  s.x += fabsf(A8.x - v.x);  s.y += fabsf(A8.y - v.y);  s.z += fabsf(A8.z - v.z);  s.w += fabsf(A8.w - v.w);
        v = q[9];  s.x += fabsf(A9.x - v.x);  s.y += fabsf(A9.y - v.y);  s.z += fabsf(A9.z - v.z);  s.w += fabsf(A9.w - v.w);
        v = q[10]; s.x += fabsf(A10.x - v.x); s.y += fabsf(A10.y - v.y); s.z += fabsf(A10.z - v.z); s.w += fabsf(A10.w - v.w);
        v = q[11]; s.x += fabsf(A11.x - v.x); s.y += fabsf(A11.y - v.y); s.z += fabsf(A11.z - v.z); s.w += fabsf(A11.w - v.w);
        v = q[12]; s.x += fabsf(A12.x - v.x); s.y += fabsf(A12.y - v.y);
        float d = (s.x + s.y) + (s.z + s.w);
        float e = __expf(-d);
        acc += (b2 == selfstep) ? 0.f : e;
    }
    part[(ch * MB_OUT + o) * B_N + b] = acc;
}

// ---------------- reduce 32 partials into h0p[:, 315:325] ----------------------
__global__ __launch_bounds__(256) void mb_reduce_kernel(
    const float* __restrict__ part, uint* __restrict__ h0p)
{
    int i = blockIdx.x * 256 + threadIdx.x;
    if (i < MB_OUT * B_N) {
        int o = i / B_N, b = i - o * B_N;
        float s = 0.f;
        #pragma unroll
        for (int ch = 0; ch < 32; ++ch)
            s += part[(ch * MB_OUT + o) * B_N + b];
        h0p[b * H0_S + FEAT + o] = pack_split(s);
    }
}

// ---------------- final layer fallback -----------------------------------------
template<int U16>
__global__ __launch_bounds__(256) void final_kernel(
    const void* __restrict__ h4v, const float* __restrict__ W5,
    const float* __restrict__ b5, float* __restrict__ out)
{
    const int wave = threadIdx.x >> 6;
    const int lane = threadIdx.x & 63;
    const int row  = blockIdx.x * 4 + wave;

    const float4 w = ((const float4*)W5)[lane];
    float s;
    if (U16) {
        const ushort* h4 = (const ushort*)h4v;
        ushort4 h = ((const ushort4*)(h4 + (size_t)row * 256))[lane];
        s = bf2f(h.x) * w.x + bf2f(h.y) * w.y + bf2f(h.z) * w.z + bf2f(h.w) * w.w;
    } else {
        const uint* h4 = (const uint*)h4v;
        uint4 h = ((const uint4*)(h4 + (size_t)row * 256))[lane];
        s = unpack_split(h.x) * w.x + unpack_split(h.y) * w.y
          + unpack_split(h.z) * w.z + unpack_split(h.w) * w.w;
    }
    #pragma unroll
    for (int off = 32; off > 0; off >>= 1)
        s += __shfl_xor(s, off);
    if (lane == 0) {
        float z = s + b5[0];
        out[row] = 1.f / (1.f + __expf(-z));
    }
}

// ---------------- launch -------------------------------------------------------
extern "C" void kernel_launch(void* const* d_in, const int* in_sizes, int n_in,
                              void* d_out, int out_size, void* d_ws, size_t ws_size,
                              hipStream_t stream)
{
    const float* ts   = (const float*)d_in[0];
    const int*   cond = (const int*)  d_in[1];
    const float* emb  = (const float*)d_in[2];
    const float* T    = (const float*)d_in[3];
    const float* W1   = (const float*)d_in[4];
    const float* b1   = (const float*)d_in[5];
    const float* W2   = (const float*)d_in[6];
    const float* b2   = (const float*)d_in[7];
    const float* W3   = (const float*)d_in[8];
    const float* b3   = (const float*)d_in[9];
    const float* W4   = (const float*)d_in[10];
    const float* b4   = (const float*)d_in[11];
    const float* W5   = (const float*)d_in[12];
    const float* b5   = (const float*)d_in[13];
    float* out = (float*)d_out;

    // workspace (4-byte units)
    uint*  h0p  = (uint*)d_ws;             // 360448
    float* M2   = (float*)(h0p + 360448);  // 655360
    uint*  h1p  = (uint*)(M2 + 655360);    // 1572864
    uint*  h2p  = h1p + 1572864;           // 1048576
    uint*  h3p  = (uint*)M2;               // alias
    uint*  h4p  = h1p;                     // alias
    float* part  = (float*)h1p;            // alias: 327680 (dead before W1)
    float* Rproj = part + 327680;          // alias: 122880 (dead before W1)
    const size_t baseU = 360448 + 655360 + 1572864 + 1048576;   // 3637248

    // packed weights: Tpu (bf16 u16, 163840 = 81920 u32) + Wb (bf16 pairs)
    ushort* Tpu = (ushort*)((uint*)d_ws + baseU);   // 320*512 ushort
    uint* Wb = (uint*)d_ws + baseU + 81920;         // 1384448 u32
    ushort* W1b = (ushort*)Wb;             // 352*1536
    ushort* W2b = W1b + 540672;            // 1536*1024
    ushort* W3b = W2b + 1572864;           // 1024*512
    ushort* W4b = W3b + 524288;            // 512*256
    const size_t packU = 81920 + 1384448;  // 1466368
    const bool packed = (ws_size / 4) >= (baseU + packU);

    const size_t pbase = packed ? baseU + packU : baseU;
    size_t capU = (ws_size / 4 > pbase) ? ws_size / 4 - pbase : 0;
    float* Pbuf = (float*)((uint*)d_ws + pbase);

    auto fits = [&](int s, int N) { return (size_t)s * B_N * N <= capU; };
    const int ST = fits(2, 512)  ? 2 : 1;
    const int S1 = fits(3, 1536) ? 3 : (fits(2, 1536) ? 2 : 1);
    const int S2 = fits(3, 1024) ? 3 : (fits(2, 1024) ? 2 : 1);
    const int S3 = fits(4, 512)  ? 4 : (fits(2, 512)  ? 2 : 1);
    const int S4 = fits(4, 256)  ? 4 : (fits(2, 256)  ? 2 : 1);

    if (packed) {
        prep_kernel<<<7456, 256, 0, stream>>>(ts, cond, emb, T, W1, W2, W3, W4,
                                              h0p, Tpu, Wb);

        // T: 2-term BK=32 (split A x bf16 T), split-K; partials reduced in proj
        {
            int kit = 10, ks = (kit + ST - 1) / ST;
            dim3 g(8, 16, ST);
            gemm_mfma2<1><<<g, 256, 0, stream>>>(h0p, Tpu, nullptr, M2,
                                                 512, H0_S, 512, 0, kit, ks, Pbuf);
        }
        { dim3 g(16, MB_OUT); proj_kernel<<<g, 256, 0, stream>>>(M2, Rproj, Pbuf, ST); }
        { dim3 g(4, MB_OUT, 32); pairwise_kernel<<<g, 256, 0, stream>>>(M2, Rproj, part); }
        mb_reduce_kernel<<<(MB_OUT * B_N + 255) / 256, 256, 0, stream>>>(part, h0p);

        ushort* h1u = (ushort*)h1p;
        ushort* h2u = (ushort*)h2p;
        ushort* h3u = (ushort*)h3p;
        ushort* h4u = (ushort*)h4p;

        // W1: 2-term BK=32 (A = split u32 h0p), bf16 out
        {
            int ks = (11 + S1 - 1) / S1;
            dim3 g(24, 16, S1);
            gemm_mfma2<0><<<g, 256, 0, stream>>>(h0p, W1b, b1, h1u, 1536, H0_S,
                                                 1536, 1536, 11, ks, Pbuf);
            if (S1 > 1) {
                dim3 ge(6, 256);
                epi_pack_kernel<0><<<ge, 256, 0, stream>>>(Pbuf, b1, h1u, 384, S1,
                                                           nullptr, nullptr, nullptr);
            }
        }
        // W2/W3/W4: 1-term bf16, BK=64; lda = producing layer's N; kit in 64-K units
        auto runL1 = [&](const ushort* in, const ushort* Wbp, const float* bia,
                         ushort* outp, int N, int lda, int kit, int S, bool fin) {
            int ks = (kit + S - 1) / S;
            dim3 g(N / 64, 16, S);
            gemm_mfma1<<<g, 256, 0, stream>>>(in, Wbp, bia, outp, N, lda, N, N,
                                              kit, ks, Pbuf);
            if (S > 1) {
                dim3 ge((N / 4) / 64, B_N / 4);
                if (fin)
                    epi_pack_kernel<1><<<ge, 256, 0, stream>>>(Pbuf, bia, outp, N / 4, S,
                                                               W5, b5, out);
                else
                    epi_pack_kernel<0><<<ge, 256, 0, stream>>>(Pbuf, bia, outp, N / 4, S,
                                                               nullptr, nullptr, nullptr);
            }
        };
        runL1(h1u, W2b, b2, h2u, 1024, 1536, 24, S2, false);
        runL1(h2u, W3b, b3, h3u,  512, 1024, 16, S3, false);
        runL1(h3u, W4b, b4, h4u,  256,  512,  8, S4, true);
        if (S4 <= 1)
            final_kernel<1><<<B_N / 4, 256, 0, stream>>>(h4u, W5, b5, out);
    } else {
        // fallback: unpacked guarded 3-term everywhere, unsplit, u32 activations
        build_x_kernel<<<B_N, 320, 0, stream>>>(ts, cond, emb, h0p);
        { dim3 g(8, 16); gemm_mfma<1,0><<<g, 256, 0, stream>>>(
              h0p, T, nullptr, M2, 500, FEAT, H0_S, 500, 0, 10, 10, Pbuf); }
        { dim3 g(16, MB_OUT); proj_kernel<<<g, 256, 0, stream>>>(M2, Rproj, nullptr, 1); }
        { dim3 g(4, MB_OUT, 32); pairwise_kernel<<<g, 256, 0, stream>>>(M2, Rproj, part); }
        mb_reduce_kernel<<<(MB_OUT * B_N + 255) / 256, 256, 0, stream>>>(part, h0p);
        { dim3 g(24, 16); gemm_mfma<0,0><<<g, 256, 0, stream>>>(
              h0p, W1, b1, h1p, 1536, H0_W, H0_S, 1536, 1536, 11, 11, Pbuf); }
        { dim3 g(16, 16); gemm_mfma<0,0><<<g, 256, 0, stream>>>(
              h1p, W2, b2, h2p, 1024, 1536, 1536, 1024, 1024, 48, 48, Pbuf); }
        { dim3 g(8, 16);  gemm_mfma<0,0><<<g, 256, 0, stream>>>(
              h2p, W3, b3, h3p, 512, 1024, 1024, 512, 512, 32, 32, Pbuf); }
        { dim3 g(4, 16);  gemm_mfma<0,0><<<g, 256, 0, stream>>>(
              h3p, W4, b4, h4p, 256, 512, 512, 256, 256, 16, 16, Pbuf); }
        final_kernel<0><<<B_N / 4, 256, 0, stream>>>(h4p, W5, b5, out);
    }
}